// Round 5
// baseline (492.278 us; speedup 1.0000x reference)
//
#include <hip/hip_runtime.h>
#include <hip/hip_bf16.h>
#include <hip/hip_fp16.h>

#define B_ 512
#define L_ 20
#define NS_ 16
#define EPS_ 32
#define H_ 128
#define V_ 100000
#define N_NODES (B_*NS_)   // 8192
#define N_EDGES (B_*EPS_)  // 16384
#define NV (V_-1)          // 99999

typedef _Float16 half8 __attribute__((ext_vector_type(8)));
typedef float floatx4 __attribute__((ext_vector_type(4)));
typedef float floatx4_a4 __attribute__((ext_vector_type(4), aligned(4)));  // 4B-aligned vec store

#define PITCH 136  // 128 f16 + 8 pad -> 272B row, 4-bank rotation, 2-way max (free)
#define GILP 385   // gi LDS pitch (f32): 2-way max
#define MGP 516    // mgh LDS pitch (f32): quad stride 4*516%32=16 -> 2-way max

// ---------------- K1: weight conversions only ----------------
__global__ void k_prep(const float* __restrict__ Wg, const float* __restrict__ Whh,
                       const float* __restrict__ Wih, const float* __restrict__ W2,
                       const float* __restrict__ W1,
                       _Float16* __restrict__ WgT_h, _Float16* __restrict__ Whh_h,
                       _Float16* __restrict__ Wih_h, _Float16* __restrict__ W2_h,
                       _Float16* __restrict__ W1_h) {
  int i = blockIdx.x*256 + threadIdx.x;
  if (i < H_*H_) { int j = i>>7, k = i&127; WgT_h[i] = (_Float16)Wg[k*H_ + j]; return; }
  i -= H_*H_;
  if (i < 3*H_*H_) { Whh_h[i] = (_Float16)Whh[i]; return; }
  i -= 3*H_*H_;
  if (i < 3*H_*H_) { Wih_h[i] = (_Float16)Wih[i]; return; }
  i -= 3*H_*H_;
  if (i < H_*H_) { W2_h[i] = (_Float16)W2[i]; return; }
  i -= H_*H_;
  if (i < H_*H_) { W1_h[i] = (_Float16)W1[i]; return; }
}

// ---------------- K2: fully-fused per-session kernel --------------------------
// Phase A (GNN step): gather emb[items] -> LDS; mgh = x @ [WgT;Whh]^T (LDS);
//   scatter-add; gi = agg @ Wih^T; GRU -> xg kept in LDS (never hits global).
// Phase B (session readout): hidden gather from LDS xg; q2 GEMM; q1 dot;
//   wave-parallel alpha; pool; hybrid; layernorm -> a_h.
// Phase-B LDS overlays the dead mgh region. Peak 74560 B -> 2 blocks/CU.
__global__ __launch_bounds__(256) void k_mega(
    const int* __restrict__ items, const int* __restrict__ edge_index,
    const int* __restrict__ sequence, const int* __restrict__ mask,
    const float* __restrict__ emb,
    const _Float16* __restrict__ Wgh, const _Float16* __restrict__ Wih,
    const _Float16* __restrict__ W2h, const _Float16* __restrict__ W1h,
    const float* __restrict__ b_ih, const float* __restrict__ b_hh,
    const float* __restrict__ b1, const float* __restrict__ b2,
    const float* __restrict__ w3, const float* __restrict__ Wt,
    const float* __restrict__ bt, const float* __restrict__ gamma,
    const float* __restrict__ beta, _Float16* __restrict__ a_h) {
  __shared__ __align__(16) char smem[74560];
  // Phase A layout
  float*    xf   = (float*)(smem);              // [16][128] fp32 x, later GRU out
  _Float16* x16  = (_Float16*)(smem + 8192);    // [16][PITCH] f16 x (MFMA A)
  float*    mghl = (float*)(smem + 12544);      // [16][MGP]  [m(128) | gh(384)]
  float*    gil  = (float*)(smem + 45568);      // [16][GILP] gi (agg aliases)
  _Float16* a16  = (_Float16*)(smem + 70208);   // [16][PITCH] f16 agg
  float*    agg  = gil;                         // dead before gil written
  // Phase B layout (overlays mghl region; xf stays live with GRU outputs)
  float*    hid    = (float*)(smem + 12544);    // [21][128] rows 0..19 hidden, 20 ht
  _Float16* h16    = (_Float16*)(smem + 23296); // [32][PITCH] f16 hidden (20..31 = 0)
  float*    qs     = (float*)(smem + 32000);    // [20][128] q2
  float*    q1full = (float*)(smem + 42240);    // [128] q1 + b1 + b2
  float*    cat    = (float*)(smem + 42752);    // [256]
  float*    alphas = (float*)(smem + 43776);    // [20]
  float*    red4   = (float*)(smem + 43856);    // [4]

  const int b = blockIdx.x, tid = threadIdx.x;
  const int w = tid >> 6, lane = tid & 63, quad = lane >> 4, r16 = lane & 15;

  // ---- A1: gather node features
  #pragma unroll
  for (int j = 0; j < 8; j++) {
    int idx = j*256 + tid;
    int n = idx >> 7, h = idx & 127;
    float v = emb[(size_t)items[b*NS_ + n]*H_ + h];
    xf[n*H_ + h] = v;
    x16[n*PITCH + h] = (_Float16)v;
  }
  __syncthreads();
  // ---- A2: mghl[16,512] = x @ Wgh[512,128]^T ; wave w owns n-tiles w*8..w*8+7
  {
    half8 afr[4];
    #pragma unroll
    for (int kk = 0; kk < 4; kk++)
      afr[kk] = *reinterpret_cast<const half8*>(&x16[r16*PITCH + kk*32 + quad*8]);
    floatx4 acc[8];
    #pragma unroll
    for (int t = 0; t < 8; t++) acc[t] = (floatx4){0.f,0.f,0.f,0.f};
    #pragma unroll
    for (int t = 0; t < 8; t++) {
      int g = w*8 + t;
      #pragma unroll
      for (int kk = 0; kk < 4; kk++) {
        half8 bfr = *reinterpret_cast<const half8*>(&Wgh[(size_t)(g*16 + r16)*H_ + kk*32 + quad*8]);
        acc[t] = __builtin_amdgcn_mfma_f32_16x16x32_f16(afr[kk], bfr, acc[t], 0, 0, 0);
      }
    }
    #pragma unroll
    for (int t = 0; t < 8; t++)
      #pragma unroll
      for (int r = 0; r < 4; r++)
        mghl[(quad*4 + r)*MGP + (w*8 + t)*16 + r16] = acc[t][r];
  }
  __syncthreads();
  // ---- A3: scatter-add m into agg; thread h owns column h (race-free)
  if (tid < 128) {
    #pragma unroll
    for (int j = 0; j < NS_; j++) agg[j*H_ + tid] = 0.f;
    for (int e = 0; e < EPS_; e++) {
      int se = edge_index[b*EPS_ + e] - b*NS_;
      int de = edge_index[N_EDGES + b*EPS_ + e] - b*NS_;
      agg[de*H_ + tid] += mghl[se*MGP + tid];
    }
  }
  __syncthreads();
  // ---- A4: agg -> f16
  #pragma unroll
  for (int j = 0; j < 8; j++) {
    int idx = j*256 + tid;
    a16[(idx >> 7)*PITCH + (idx & 127)] = (_Float16)agg[idx];
  }
  __syncthreads();
  // ---- A5: gil[16,384] = agg @ Wih[384,128]^T ; wave w owns n-tiles w*6..w*6+5
  {
    half8 afr[4];
    #pragma unroll
    for (int kk = 0; kk < 4; kk++)
      afr[kk] = *reinterpret_cast<const half8*>(&a16[r16*PITCH + kk*32 + quad*8]);
    floatx4 acc[6];
    #pragma unroll
    for (int t = 0; t < 6; t++) acc[t] = (floatx4){0.f,0.f,0.f,0.f};
    #pragma unroll
    for (int t = 0; t < 6; t++) {
      int g = w*6 + t;
      #pragma unroll
      for (int kk = 0; kk < 4; kk++) {
        half8 bfr = *reinterpret_cast<const half8*>(&Wih[(size_t)(g*16 + r16)*H_ + kk*32 + quad*8]);
        acc[t] = __builtin_amdgcn_mfma_f32_16x16x32_f16(afr[kk], bfr, acc[t], 0, 0, 0);
      }
    }
    #pragma unroll
    for (int t = 0; t < 6; t++)
      #pragma unroll
      for (int r = 0; r < 4; r++)
        gil[(quad*4 + r)*GILP + (w*6 + t)*16 + r16] = acc[t][r];
  }
  __syncthreads();
  // ---- A6: GRU epilogue -> xf in place (per-element read-then-write, no hazard)
  #pragma unroll
  for (int j = 0; j < 8; j++) {
    int idx = j*256 + tid;
    int nl = idx >> 7, h = idx & 127;
    float ir  = gil[nl*GILP + h]       + b_ih[h];
    float iz  = gil[nl*GILP + 128 + h] + b_ih[128 + h];
    float in_ = gil[nl*GILP + 256 + h] + b_ih[256 + h];
    float hr  = mghl[nl*MGP + 128 + h] + b_hh[h];
    float hz  = mghl[nl*MGP + 256 + h] + b_hh[128 + h];
    float hn  = mghl[nl*MGP + 384 + h] + b_hh[256 + h];
    float rr = 1.f/(1.f + __expf(-(ir + hr)));
    float zz = 1.f/(1.f + __expf(-(iz + hz)));
    float nn = tanhf(in_ + rr*hn);
    float hp = xf[nl*H_ + h];
    xf[nl*H_ + h] = (1.f - zz)*nn + zz*hp;
  }
  __syncthreads();
  // ---- B1: hidden gather from LDS xg (phase-B overlay of mghl begins here)
  int len = 0;
  #pragma unroll
  for (int i = 0; i < L_; i++) len += mask[b*L_ + i];
  #pragma unroll
  for (int j = 0; j < 10; j++) {
    int r = j*2 + (tid >> 7);
    int h = tid & 127;
    int seqv = sequence[b*L_ + r];
    float val = 0.f;
    if (seqv != 0) {
      int idx = -1;
      #pragma unroll
      for (int jj = 0; jj < NS_; jj++) { if (idx < 0 && items[b*NS_ + jj] == seqv) idx = jj; }
      val = (idx >= 0) ? xf[idx*H_ + h] : emb[(size_t)seqv*H_ + h];
    }
    hid[r*H_ + h] = val;
    h16[r*PITCH + h] = (_Float16)val;
  }
  #pragma unroll
  for (int j = 0; j < 6; j++) {   // zero f16 pad rows 20..31 (cols 0..127)
    int idx = j*256 + tid;
    h16[(20 + (idx >> 7))*PITCH + (idx & 127)] = (_Float16)0.f;
  }
  __syncthreads();
  if (tid < 128) hid[20*H_ + tid] = hid[(len-1)*H_ + tid];   // ht
  __syncthreads();
  // ---- B2: q2[20,128] = hidden @ W2^T (M-tile 32, N=128, K=128)
  {
    half8 afr[2][4];
    #pragma unroll
    for (int mt = 0; mt < 2; mt++)
      #pragma unroll
      for (int kk = 0; kk < 4; kk++)
        afr[mt][kk] = *reinterpret_cast<const half8*>(&h16[(mt*16 + r16)*PITCH + kk*32 + quad*8]);
    floatx4 acc[2][2];
    #pragma unroll
    for (int mt = 0; mt < 2; mt++)
      #pragma unroll
      for (int nt = 0; nt < 2; nt++) acc[mt][nt] = (floatx4){0.f,0.f,0.f,0.f};
    #pragma unroll
    for (int nt = 0; nt < 2; nt++) {
      #pragma unroll
      for (int kk = 0; kk < 4; kk++) {
        half8 bfr = *reinterpret_cast<const half8*>(&W2h[(size_t)((w*2 + nt)*16 + r16)*H_ + kk*32 + quad*8]);
        acc[0][nt] = __builtin_amdgcn_mfma_f32_16x16x32_f16(afr[0][kk], bfr, acc[0][nt], 0, 0, 0);
        acc[1][nt] = __builtin_amdgcn_mfma_f32_16x16x32_f16(afr[1][kk], bfr, acc[1][nt], 0, 0, 0);
      }
    }
    #pragma unroll
    for (int mt = 0; mt < 2; mt++)
      #pragma unroll
      for (int nt = 0; nt < 2; nt++)
        #pragma unroll
        for (int r = 0; r < 4; r++) {
          int row = mt*16 + quad*4 + r;
          if (row < 20) qs[row*H_ + (w*2 + nt)*16 + r16] = acc[mt][nt][r];
        }
  }
  // ---- B3: q1[t] = b1+b2 + ht(fp32) . W1(f16 row t)
  if (tid < 128) {
    float s = b1[tid] + b2[tid];
    const half8* wrow = reinterpret_cast<const half8*>(&W1h[(size_t)tid*H_]);
    #pragma unroll
    for (int k8 = 0; k8 < 16; k8++) {
      half8 hv = wrow[k8];
      #pragma unroll
      for (int u = 0; u < 8; u++) s += hid[20*H_ + k8*8 + u] * (float)hv[u];
    }
    q1full[tid] = s;
  }
  __syncthreads();
  // ---- B4: alpha; wave w -> positions w*5 .. w*5+4
  for (int j = 0; j < 5; j++) {
    int l = w*5 + j;
    float v = 0.f;
    #pragma unroll
    for (int p = 0; p < 2; p++) {
      int t = lane + p*64;
      float s = q1full[t] + qs[l*H_ + t];
      v += (1.f/(1.f + __expf(-s))) * w3[t];
    }
    #pragma unroll
    for (int o = 32; o > 0; o >>= 1) v += __shfl_down(v, o);
    if (lane == 0) alphas[l] = v;
  }
  __syncthreads();
  // ---- B5: attention pool + cat
  if (tid < 128) {
    float af = 0.f;
    #pragma unroll
    for (int l = 0; l < L_; l++) af += alphas[l]*hid[l*H_ + tid];
    cat[tid] = af; cat[128 + tid] = hid[20*H_ + tid];
  }
  __syncthreads();
  // ---- B6: hybrid transform + layernorm -> a_h
  float hyb = 0.f;
  if (tid < 128) {
    hyb = bt[tid];
    const float* wrow = &Wt[(size_t)tid*256];
    #pragma unroll 4
    for (int k = 0; k < 256; k++) hyb += cat[k]*wrow[k];
  }
  float s1 = (tid < 128) ? hyb : 0.f;
  #pragma unroll
  for (int o = 32; o > 0; o >>= 1) s1 += __shfl_down(s1, o);
  if (lane == 0) red4[w] = s1;
  __syncthreads();
  float mu = (red4[0] + red4[1] + red4[2] + red4[3]) * (1.f/128.f);
  __syncthreads();
  float d = (tid < 128) ? (hyb - mu) : 0.f;
  float s2 = d*d;
  #pragma unroll
  for (int o = 32; o > 0; o >>= 1) s2 += __shfl_down(s2, o);
  if (lane == 0) red4[w] = s2;
  __syncthreads();
  if (tid < 128) {
    float var = (red4[0] + red4[1] + red4[2] + red4[3]) * (1.f/128.f);
    float y = d * rsqrtf(var + 1e-5f) * gamma[tid] + beta[tid];
    a_h[(size_t)b*H_ + tid] = (_Float16)y;
  }
}

// ---------------- K3: scores = a * emb[1:]^T  [512, 99999] fp32 out --------------
// grid 1563 nt-blocks x 512 thr (8 waves). M=512 in one block: emb tile read ONCE;
// A-fragments loaded directly from L2-resident a_h. OPERAND-SWAPPED MFMA: thread
// owns 1 row x 4 consecutive cols -> one 16B nontemporal store per tile (16 vs 64
// store instrs/thread). Products & accumulation order identical -> bitwise-same C.
__global__ __launch_bounds__(512) void k_scores(
    const _Float16* __restrict__ a_h, const float* __restrict__ emb,
    float* __restrict__ out) {
  __shared__ _Float16 lds_b[64*PITCH];
  const int tid = threadIdx.x;
  const int nt = blockIdx.x;
  // stage B: 64 emb rows fp32 -> f16 (guard last tile): 2048 float4-chunks = 4*512
  #pragma unroll
  for (int i = 0; i < 4; i++) {
    int lin = i*512 + tid;
    int row = lin >> 5, c4 = lin & 31;
    int g = nt*64 + row;
    float4 v = {0.f, 0.f, 0.f, 0.f};
    if (g < NV) v = *reinterpret_cast<const float4*>(&emb[(size_t)(1 + g)*H_ + c4*4]);
    union { _Float16 h[4]; uint2 u; } p;
    p.h[0]=(_Float16)v.x; p.h[1]=(_Float16)v.y; p.h[2]=(_Float16)v.z; p.h[3]=(_Float16)v.w;
    *reinterpret_cast<uint2*>(&lds_b[row*PITCH + c4*4]) = p.u;
  }
  __syncthreads();
  const int w = tid >> 6, lane = tid & 63, quad = lane >> 4, r16 = lane & 15;
  floatx4 acc[4][4];
  #pragma unroll
  for (int ms = 0; ms < 4; ms++)
    #pragma unroll
    for (int n4 = 0; n4 < 4; n4++) acc[ms][n4] = (floatx4){0.f,0.f,0.f,0.f};
  #pragma unroll
  for (int ms = 0; ms < 4; ms++) {
    half8 afr[4];
    #pragma unroll
    for (int kk = 0; kk < 4; kk++)
      afr[kk] = *reinterpret_cast<const half8*>(&a_h[(size_t)(w*64 + ms*16 + r16)*H_ + kk*32 + quad*8]);
    #pragma unroll
    for (int n4 = 0; n4 < 4; n4++) {
      #pragma unroll
      for (int kk = 0; kk < 4; kk++) {
        half8 bfr = *reinterpret_cast<const half8*>(&lds_b[(n4*16 + r16)*PITCH + kk*32 + quad*8]);
        // swapped operands: D[i=emb-row, j=a-row]; lane holds j=r16, i=quad*4+reg
        acc[ms][n4] = __builtin_amdgcn_mfma_f32_16x16x32_f16(bfr, afr[kk], acc[ms][n4], 0, 0, 0);
      }
    }
  }
  #pragma unroll
  for (int ms = 0; ms < 4; ms++) {
    int row = w*64 + ms*16 + r16;
    #pragma unroll
    for (int n4 = 0; n4 < 4; n4++) {
      int col0 = nt*64 + n4*16 + quad*4;
      if (col0 + 3 < NV) {
        floatx4_a4 v = { acc[ms][n4][0], acc[ms][n4][1], acc[ms][n4][2], acc[ms][n4][3] };
        __builtin_nontemporal_store(v,
            reinterpret_cast<floatx4_a4*>(&out[(size_t)row*NV + col0]));
      } else {
        #pragma unroll
        for (int r = 0; r < 4; r++)
          if (col0 + r < NV) out[(size_t)row*NV + col0 + r] = acc[ms][n4][r];
      }
    }
  }
}

extern "C" void kernel_launch(void* const* d_in, const int* in_sizes, int n_in,
                              void* d_out, int out_size, void* d_ws, size_t ws_size,
                              hipStream_t stream) {
  const int*   items     = (const int*)d_in[0];
  const int*   edge_index= (const int*)d_in[1];
  const int*   sequence  = (const int*)d_in[2];
  const int*   mask      = (const int*)d_in[3];
  const float* emb       = (const float*)d_in[4];
  const float* ggnn_w    = (const float*)d_in[5];
  const float* W_ih      = (const float*)d_in[6];
  const float* W_hh      = (const float*)d_in[7];
  const float* b_ih      = (const float*)d_in[8];
  const float* b_hh      = (const float*)d_in[9];
  const float* W1        = (const float*)d_in[10];
  const float* b1        = (const float*)d_in[11];
  const float* W2        = (const float*)d_in[12];
  const float* b2        = (const float*)d_in[13];
  const float* w3        = (const float*)d_in[14];
  const float* Wt        = (const float*)d_in[15];
  const float* bt        = (const float*)d_in[16];
  const float* gamma     = (const float*)d_in[17];
  const float* beta      = (const float*)d_in[18];

  char* ws = (char*)d_ws;
  _Float16* a_h   = (_Float16*)(ws + 39059456);
  _Float16* WgT_h = (_Float16*)(ws + 39190528);
  _Float16* Whh_h = (_Float16*)(ws + 39223296); // contiguous after WgT_h ([WgT;Whh])
  _Float16* Wih_h = (_Float16*)(ws + 39321600);
  _Float16* W2_h  = (_Float16*)(ws + 39419904);
  _Float16* W1_h  = (_Float16*)(ws + 39452672);
  float* out = (float*)d_out;

  // K1: f16 weight conversions (147456 elems = 576*256)
  k_prep<<<576, 256, 0, stream>>>(ggnn_w, W_hh, W_ih, W2, W1,
                                  WgT_h, Whh_h, Wih_h, W2_h, W1_h);
  // K2: fully-fused per-session GNN + readout (xg never leaves LDS)
  k_mega<<<512, 256, 0, stream>>>(items, edge_index, sequence, mask, emb,
                                  WgT_h, Wih_h, W2_h, W1_h, b_ih, b_hh,
                                  b1, b2, w3, Wt, bt, gamma, beta, a_h);
  // K3: scores = a * emb[1:]^T (single-pass M=512, swapped-MFMA float4 nt stores)
  k_scores<<<1563, 512, 0, stream>>>(a_h, emb, out);
}

// Round 8
// 386.574 us; speedup vs baseline: 1.2734x; 1.2734x over previous
//
#include <hip/hip_runtime.h>
#include <hip/hip_bf16.h>
#include <hip/hip_fp16.h>

#define B_ 512
#define L_ 20
#define NS_ 16
#define EPS_ 32
#define H_ 128
#define V_ 100000
#define N_NODES (B_*NS_)   // 8192
#define N_EDGES (B_*EPS_)  // 16384
#define NV (V_-1)          // 99999

typedef _Float16 half8 __attribute__((ext_vector_type(8)));
typedef float floatx4 __attribute__((ext_vector_type(4)));

#define PITCH 136  // 128 f16 + 8 pad -> 272B row, 4-bank rotation, 2-way max (free)
#define GILP 385   // gi LDS pitch (f32): 2-way max
#define MGP 516    // mgh LDS pitch (f32): quad stride 4*516%32=16 -> 2-way max

// ---------------- K1: weight conversions only ----------------
__global__ void k_prep(const float* __restrict__ Wg, const float* __restrict__ Whh,
                       const float* __restrict__ Wih, const float* __restrict__ W2,
                       const float* __restrict__ W1,
                       _Float16* __restrict__ WgT_h, _Float16* __restrict__ Whh_h,
                       _Float16* __restrict__ Wih_h, _Float16* __restrict__ W2_h,
                       _Float16* __restrict__ W1_h) {
  int i = blockIdx.x*256 + threadIdx.x;
  if (i < H_*H_) { int j = i>>7, k = i&127; WgT_h[i] = (_Float16)Wg[k*H_ + j]; return; }
  i -= H_*H_;
  if (i < 3*H_*H_) { Whh_h[i] = (_Float16)Whh[i]; return; }
  i -= 3*H_*H_;
  if (i < 3*H_*H_) { Wih_h[i] = (_Float16)Wih[i]; return; }
  i -= 3*H_*H_;
  if (i < H_*H_) { W2_h[i] = (_Float16)W2[i]; return; }
  i -= H_*H_;
  if (i < H_*H_) { W1_h[i] = (_Float16)W1[i]; return; }
}

// ---------------- K2: fully-fused per-session kernel --------------------------
// Phase A (GNN step): gather emb[items] -> LDS; mgh = x @ [WgT;Whh]^T (LDS);
//   scatter-add; gi = agg @ Wih^T; GRU -> xg kept in LDS (never hits global).
// Phase B (session readout): hidden gather from LDS xg; q2 GEMM; q1 dot;
//   wave-parallel alpha; pool; hybrid; layernorm -> a_h.
// Phase-B LDS overlays the dead mgh region. Peak 74560 B -> 2 blocks/CU.
__global__ __launch_bounds__(256) void k_mega(
    const int* __restrict__ items, const int* __restrict__ edge_index,
    const int* __restrict__ sequence, const int* __restrict__ mask,
    const float* __restrict__ emb,
    const _Float16* __restrict__ Wgh, const _Float16* __restrict__ Wih,
    const _Float16* __restrict__ W2h, const _Float16* __restrict__ W1h,
    const float* __restrict__ b_ih, const float* __restrict__ b_hh,
    const float* __restrict__ b1, const float* __restrict__ b2,
    const float* __restrict__ w3, const float* __restrict__ Wt,
    const float* __restrict__ bt, const float* __restrict__ gamma,
    const float* __restrict__ beta, _Float16* __restrict__ a_h) {
  __shared__ __align__(16) char smem[74560];
  // Phase A layout
  float*    xf   = (float*)(smem);              // [16][128] fp32 x, later GRU out
  _Float16* x16  = (_Float16*)(smem + 8192);    // [16][PITCH] f16 x (MFMA A)
  float*    mghl = (float*)(smem + 12544);      // [16][MGP]  [m(128) | gh(384)]
  float*    gil  = (float*)(smem + 45568);      // [16][GILP] gi (agg aliases)
  _Float16* a16  = (_Float16*)(smem + 70208);   // [16][PITCH] f16 agg
  float*    agg  = gil;                         // dead before gil written
  // Phase B layout (overlays mghl region; xf stays live with GRU outputs)
  float*    hid    = (float*)(smem + 12544);    // [21][128] rows 0..19 hidden, 20 ht
  _Float16* h16    = (_Float16*)(smem + 23296); // [32][PITCH] f16 hidden (20..31 = 0)
  float*    qs     = (float*)(smem + 32000);    // [20][128] q2
  float*    q1full = (float*)(smem + 42240);    // [128] q1 + b1 + b2
  float*    cat    = (float*)(smem + 42752);    // [256]
  float*    alphas = (float*)(smem + 43776);    // [20]
  float*    red4   = (float*)(smem + 43856);    // [4]

  const int b = blockIdx.x, tid = threadIdx.x;
  const int w = tid >> 6, lane = tid & 63, quad = lane >> 4, r16 = lane & 15;

  // ---- A1: gather node features
  #pragma unroll
  for (int j = 0; j < 8; j++) {
    int idx = j*256 + tid;
    int n = idx >> 7, h = idx & 127;
    float v = emb[(size_t)items[b*NS_ + n]*H_ + h];
    xf[n*H_ + h] = v;
    x16[n*PITCH + h] = (_Float16)v;
  }
  __syncthreads();
  // ---- A2: mghl[16,512] = x @ Wgh[512,128]^T ; wave w owns n-tiles w*8..w*8+7
  {
    half8 afr[4];
    #pragma unroll
    for (int kk = 0; kk < 4; kk++)
      afr[kk] = *reinterpret_cast<const half8*>(&x16[r16*PITCH + kk*32 + quad*8]);
    floatx4 acc[8];
    #pragma unroll
    for (int t = 0; t < 8; t++) acc[t] = (floatx4){0.f,0.f,0.f,0.f};
    #pragma unroll
    for (int t = 0; t < 8; t++) {
      int g = w*8 + t;
      #pragma unroll
      for (int kk = 0; kk < 4; kk++) {
        half8 bfr = *reinterpret_cast<const half8*>(&Wgh[(size_t)(g*16 + r16)*H_ + kk*32 + quad*8]);
        acc[t] = __builtin_amdgcn_mfma_f32_16x16x32_f16(afr[kk], bfr, acc[t], 0, 0, 0);
      }
    }
    #pragma unroll
    for (int t = 0; t < 8; t++)
      #pragma unroll
      for (int r = 0; r < 4; r++)
        mghl[(quad*4 + r)*MGP + (w*8 + t)*16 + r16] = acc[t][r];
  }
  __syncthreads();
  // ---- A3: scatter-add m into agg; thread h owns column h (race-free)
  if (tid < 128) {
    #pragma unroll
    for (int j = 0; j < NS_; j++) agg[j*H_ + tid] = 0.f;
    for (int e = 0; e < EPS_; e++) {
      int se = edge_index[b*EPS_ + e] - b*NS_;
      int de = edge_index[N_EDGES + b*EPS_ + e] - b*NS_;
      agg[de*H_ + tid] += mghl[se*MGP + tid];
    }
  }
  __syncthreads();
  // ---- A4: agg -> f16
  #pragma unroll
  for (int j = 0; j < 8; j++) {
    int idx = j*256 + tid;
    a16[(idx >> 7)*PITCH + (idx & 127)] = (_Float16)agg[idx];
  }
  __syncthreads();
  // ---- A5: gil[16,384] = agg @ Wih[384,128]^T ; wave w owns n-tiles w*6..w*6+5
  {
    half8 afr[4];
    #pragma unroll
    for (int kk = 0; kk < 4; kk++)
      afr[kk] = *reinterpret_cast<const half8*>(&a16[r16*PITCH + kk*32 + quad*8]);
    floatx4 acc[6];
    #pragma unroll
    for (int t = 0; t < 6; t++) acc[t] = (floatx4){0.f,0.f,0.f,0.f};
    #pragma unroll
    for (int t = 0; t < 6; t++) {
      int g = w*6 + t;
      #pragma unroll
      for (int kk = 0; kk < 4; kk++) {
        half8 bfr = *reinterpret_cast<const half8*>(&Wih[(size_t)(g*16 + r16)*H_ + kk*32 + quad*8]);
        acc[t] = __builtin_amdgcn_mfma_f32_16x16x32_f16(afr[kk], bfr, acc[t], 0, 0, 0);
      }
    }
    #pragma unroll
    for (int t = 0; t < 6; t++)
      #pragma unroll
      for (int r = 0; r < 4; r++)
        gil[(quad*4 + r)*GILP + (w*6 + t)*16 + r16] = acc[t][r];
  }
  __syncthreads();
  // ---- A6: GRU epilogue -> xf in place (per-element read-then-write, no hazard)
  #pragma unroll
  for (int j = 0; j < 8; j++) {
    int idx = j*256 + tid;
    int nl = idx >> 7, h = idx & 127;
    float ir  = gil[nl*GILP + h]       + b_ih[h];
    float iz  = gil[nl*GILP + 128 + h] + b_ih[128 + h];
    float in_ = gil[nl*GILP + 256 + h] + b_ih[256 + h];
    float hr  = mghl[nl*MGP + 128 + h] + b_hh[h];
    float hz  = mghl[nl*MGP + 256 + h] + b_hh[128 + h];
    float hn  = mghl[nl*MGP + 384 + h] + b_hh[256 + h];
    float rr = 1.f/(1.f + __expf(-(ir + hr)));
    float zz = 1.f/(1.f + __expf(-(iz + hz)));
    float nn = tanhf(in_ + rr*hn);
    float hp = xf[nl*H_ + h];
    xf[nl*H_ + h] = (1.f - zz)*nn + zz*hp;
  }
  __syncthreads();
  // ---- B1: hidden gather from LDS xg (phase-B overlay of mghl begins here)
  int len = 0;
  #pragma unroll
  for (int i = 0; i < L_; i++) len += mask[b*L_ + i];
  #pragma unroll
  for (int j = 0; j < 10; j++) {
    int r = j*2 + (tid >> 7);
    int h = tid & 127;
    int seqv = sequence[b*L_ + r];
    float val = 0.f;
    if (seqv != 0) {
      int idx = -1;
      #pragma unroll
      for (int jj = 0; jj < NS_; jj++) { if (idx < 0 && items[b*NS_ + jj] == seqv) idx = jj; }
      val = (idx >= 0) ? xf[idx*H_ + h] : emb[(size_t)seqv*H_ + h];
    }
    hid[r*H_ + h] = val;
    h16[r*PITCH + h] = (_Float16)val;
  }
  #pragma unroll
  for (int j = 0; j < 6; j++) {   // zero f16 pad rows 20..31 (cols 0..127)
    int idx = j*256 + tid;
    h16[(20 + (idx >> 7))*PITCH + (idx & 127)] = (_Float16)0.f;
  }
  __syncthreads();
  if (tid < 128) hid[20*H_ + tid] = hid[(len-1)*H_ + tid];   // ht
  __syncthreads();
  // ---- B2: q2[20,128] = hidden @ W2^T (M-tile 32, N=128, K=128)
  {
    half8 afr[2][4];
    #pragma unroll
    for (int mt = 0; mt < 2; mt++)
      #pragma unroll
      for (int kk = 0; kk < 4; kk++)
        afr[mt][kk] = *reinterpret_cast<const half8*>(&h16[(mt*16 + r16)*PITCH + kk*32 + quad*8]);
    floatx4 acc[2][2];
    #pragma unroll
    for (int mt = 0; mt < 2; mt++)
      #pragma unroll
      for (int nt = 0; nt < 2; nt++) acc[mt][nt] = (floatx4){0.f,0.f,0.f,0.f};
    #pragma unroll
    for (int nt = 0; nt < 2; nt++) {
      #pragma unroll
      for (int kk = 0; kk < 4; kk++) {
        half8 bfr = *reinterpret_cast<const half8*>(&W2h[(size_t)((w*2 + nt)*16 + r16)*H_ + kk*32 + quad*8]);
        acc[0][nt] = __builtin_amdgcn_mfma_f32_16x16x32_f16(afr[0][kk], bfr, acc[0][nt], 0, 0, 0);
        acc[1][nt] = __builtin_amdgcn_mfma_f32_16x16x32_f16(afr[1][kk], bfr, acc[1][nt], 0, 0, 0);
      }
    }
    #pragma unroll
    for (int mt = 0; mt < 2; mt++)
      #pragma unroll
      for (int nt = 0; nt < 2; nt++)
        #pragma unroll
        for (int r = 0; r < 4; r++) {
          int row = mt*16 + quad*4 + r;
          if (row < 20) qs[row*H_ + (w*2 + nt)*16 + r16] = acc[mt][nt][r];
        }
  }
  // ---- B3: q1[t] = b1+b2 + ht(fp32) . W1(f16 row t)
  if (tid < 128) {
    float s = b1[tid] + b2[tid];
    const half8* wrow = reinterpret_cast<const half8*>(&W1h[(size_t)tid*H_]);
    #pragma unroll
    for (int k8 = 0; k8 < 16; k8++) {
      half8 hv = wrow[k8];
      #pragma unroll
      for (int u = 0; u < 8; u++) s += hid[20*H_ + k8*8 + u] * (float)hv[u];
    }
    q1full[tid] = s;
  }
  __syncthreads();
  // ---- B4: alpha; wave w -> positions w*5 .. w*5+4
  for (int j = 0; j < 5; j++) {
    int l = w*5 + j;
    float v = 0.f;
    #pragma unroll
    for (int p = 0; p < 2; p++) {
      int t = lane + p*64;
      float s = q1full[t] + qs[l*H_ + t];
      v += (1.f/(1.f + __expf(-s))) * w3[t];
    }
    #pragma unroll
    for (int o = 32; o > 0; o >>= 1) v += __shfl_down(v, o);
    if (lane == 0) alphas[l] = v;
  }
  __syncthreads();
  // ---- B5: attention pool + cat
  if (tid < 128) {
    float af = 0.f;
    #pragma unroll
    for (int l = 0; l < L_; l++) af += alphas[l]*hid[l*H_ + tid];
    cat[tid] = af; cat[128 + tid] = hid[20*H_ + tid];
  }
  __syncthreads();
  // ---- B6: hybrid transform + layernorm -> a_h
  float hyb = 0.f;
  if (tid < 128) {
    hyb = bt[tid];
    const float* wrow = &Wt[(size_t)tid*256];
    #pragma unroll 4
    for (int k = 0; k < 256; k++) hyb += cat[k]*wrow[k];
  }
  float s1 = (tid < 128) ? hyb : 0.f;
  #pragma unroll
  for (int o = 32; o > 0; o >>= 1) s1 += __shfl_down(s1, o);
  if (lane == 0) red4[w] = s1;
  __syncthreads();
  float mu = (red4[0] + red4[1] + red4[2] + red4[3]) * (1.f/128.f);
  __syncthreads();
  float d = (tid < 128) ? (hyb - mu) : 0.f;
  float s2 = d*d;
  #pragma unroll
  for (int o = 32; o > 0; o >>= 1) s2 += __shfl_down(s2, o);
  if (lane == 0) red4[w] = s2;
  __syncthreads();
  if (tid < 128) {
    float var = (red4[0] + red4[1] + red4[2] + red4[3]) * (1.f/128.f);
    float y = d * rsqrtf(var + 1e-5f) * gamma[tid] + beta[tid];
    a_h[(size_t)b*H_ + tid] = (_Float16)y;
  }
}

// ---------------- K3: scores = a * emb[1:]^T  [512, 99999] fp32 out --------------
// R4-measured compute/store path (unswapped MFMA, coalesced dword stores).
// Bijective chunked XCD swizzle (q=195,r=3): each XCD owns a contiguous nt range
// -> co-resident neighbor tiles share one L2 -> partial edge cache lines (out
// rows are 60-mod-64 misaligned) merge before eviction, avoiding RMW.
__global__ __launch_bounds__(512) void k_scores(
    const _Float16* __restrict__ a_h, const float* __restrict__ emb,
    float* __restrict__ out) {
  __shared__ _Float16 lds_b[64*PITCH];
  const int tid = threadIdx.x;
  // bijective chunked XCD remap of 1563 tiles over 8 XCDs (HW: block d -> XCD d%8)
  const int d = blockIdx.x;
  const int q = 1563/8, rr = 1563%8;           // 195, 3
  const int xcd = d & 7, idx = d >> 3;
  const int nt = (xcd < rr) ? xcd*(q+1) + idx
                            : rr*(q+1) + (xcd - rr)*q + idx;
  // stage B: 64 emb rows fp32 -> f16 (guard last tile): 2048 float4-chunks = 4*512
  #pragma unroll
  for (int i = 0; i < 4; i++) {
    int lin = i*512 + tid;
    int row = lin >> 5, c4 = lin & 31;
    int g = nt*64 + row;
    float4 v = {0.f, 0.f, 0.f, 0.f};
    if (g < NV) v = *reinterpret_cast<const float4*>(&emb[(size_t)(1 + g)*H_ + c4*4]);
    union { _Float16 h[4]; uint2 u; } p;
    p.h[0]=(_Float16)v.x; p.h[1]=(_Float16)v.y; p.h[2]=(_Float16)v.z; p.h[3]=(_Float16)v.w;
    *reinterpret_cast<uint2*>(&lds_b[row*PITCH + c4*4]) = p.u;
  }
  __syncthreads();
  const int w = tid >> 6, lane = tid & 63, quad = lane >> 4, r16 = lane & 15;
  floatx4 acc[4][4];
  #pragma unroll
  for (int ms = 0; ms < 4; ms++)
    #pragma unroll
    for (int n4 = 0; n4 < 4; n4++) acc[ms][n4] = (floatx4){0.f,0.f,0.f,0.f};
  #pragma unroll
  for (int ms = 0; ms < 4; ms++) {
    half8 afr[4];
    #pragma unroll
    for (int kk = 0; kk < 4; kk++)
      afr[kk] = *reinterpret_cast<const half8*>(&a_h[(size_t)(w*64 + ms*16 + r16)*H_ + kk*32 + quad*8]);
    #pragma unroll
    for (int n4 = 0; n4 < 4; n4++) {
      #pragma unroll
      for (int kk = 0; kk < 4; kk++) {
        half8 bfr = *reinterpret_cast<const half8*>(&lds_b[(n4*16 + r16)*PITCH + kk*32 + quad*8]);
        acc[ms][n4] = __builtin_amdgcn_mfma_f32_16x16x32_f16(afr[kk], bfr, acc[ms][n4], 0, 0, 0);
      }
    }
  }
  #pragma unroll
  for (int ms = 0; ms < 4; ms++)
    #pragma unroll
    for (int n4 = 0; n4 < 4; n4++)
      #pragma unroll
      for (int r = 0; r < 4; r++) {
        int row = w*64 + ms*16 + quad*4 + r;
        int col = nt*64 + n4*16 + r16;
        if (col < NV) out[(size_t)row*NV + col] = acc[ms][n4][r];
      }
}

extern "C" void kernel_launch(void* const* d_in, const int* in_sizes, int n_in,
                              void* d_out, int out_size, void* d_ws, size_t ws_size,
                              hipStream_t stream) {
  const int*   items     = (const int*)d_in[0];
  const int*   edge_index= (const int*)d_in[1];
  const int*   sequence  = (const int*)d_in[2];
  const int*   mask      = (const int*)d_in[3];
  const float* emb       = (const float*)d_in[4];
  const float* ggnn_w    = (const float*)d_in[5];
  const float* W_ih      = (const float*)d_in[6];
  const float* W_hh      = (const float*)d_in[7];
  const float* b_ih      = (const float*)d_in[8];
  const float* b_hh      = (const float*)d_in[9];
  const float* W1        = (const float*)d_in[10];
  const float* b1        = (const float*)d_in[11];
  const float* W2        = (const float*)d_in[12];
  const float* b2        = (const float*)d_in[13];
  const float* w3        = (const float*)d_in[14];
  const float* Wt        = (const float*)d_in[15];
  const float* bt        = (const float*)d_in[16];
  const float* gamma     = (const float*)d_in[17];
  const float* beta      = (const float*)d_in[18];

  char* ws = (char*)d_ws;
  _Float16* a_h   = (_Float16*)(ws + 39059456);
  _Float16* WgT_h = (_Float16*)(ws + 39190528);
  _Float16* Whh_h = (_Float16*)(ws + 39223296); // contiguous after WgT_h ([WgT;Whh])
  _Float16* Wih_h = (_Float16*)(ws + 39321600);
  _Float16* W2_h  = (_Float16*)(ws + 39419904);
  _Float16* W1_h  = (_Float16*)(ws + 39452672);
  float* out = (float*)d_out;

  // K1: f16 weight conversions (147456 elems = 576*256)
  k_prep<<<576, 256, 0, stream>>>(ggnn_w, W_hh, W_ih, W2, W1,
                                  WgT_h, Whh_h, Wih_h, W2_h, W1_h);
  // K2: fully-fused per-session GNN + readout (xg never leaves LDS)
  k_mega<<<512, 256, 0, stream>>>(items, edge_index, sequence, mask, emb,
                                  WgT_h, Wih_h, W2_h, W1_h, b_ih, b_hh,
                                  b1, b2, w3, Wt, bt, gamma, beta, a_h);
  // K3: scores = a * emb[1:]^T (R4 store path + chunked XCD swizzle)
  k_scores<<<1563, 512, 0, stream>>>(a_h, emb, out);
}